// Round 1
// baseline (305.274 us; speedup 1.0000x reference)
//
#include <hip/hip_runtime.h>
#include <math.h>

// NerfHead: fused ray-march + trilinear + online transmittance + 3 losses.
// One wave (64 lanes) per ray, 4 rays per 256-thread block.
// Global accumulators in d_ws: [0]=sum_wy_nll [1]=sum_wy [2]=sum_ent
// [3]=n_valid [4]=sum_bi [5]=sum_w2 [6]=n_pk
//
// R1 change vs 748.8us baseline: semantic corner gathers vectorized
// (17 scalar dword -> 4x dwordx4 + 1 dword per corner; 4B-aligned wide
// loads are legal on gfx950). Theory: kernel is scattered-VMEM-request-
// throughput bound, so cutting request count ~3x on the dominant path
// should cut dur_us ~2x. Also: block-level LDS pre-reduction before the
// global atomics (4x fewer global atomics on one hot cache line).

#define DXX 200
#define DYY 200
#define DZZ 16
#define NC 17
#define S_TOT 416
#define N_IN 390
#define CHUNKS 7
#define RPB 4   // rays per block

// 4-float vector with 4-byte alignment: lets the compiler emit
// global_load_dwordx4 at the 68B-strided (4B-aligned) semantic rows.
typedef float v4u __attribute__((ext_vector_type(4), aligned(4), may_alias));

__constant__ double c_freq[NC] = {1163161.0, 2309034.0, 188743.0, 2997643.0,
  20317180.0, 852476.0, 243808.0, 2457947.0, 497017.0, 2731022.0, 7224789.0,
  214411435.0, 5565043.0, 63191967.0, 76098082.0, 128860031.0, 141625221.0};

__device__ __forceinline__ float iscan_add(float x, int lane) {
#pragma unroll
  for (int off = 1; off < 64; off <<= 1) {
    float y = __shfl_up(x, off);
    if (lane >= off) x += y;
  }
  return x;
}
__device__ __forceinline__ float iscan_mul(float x, int lane) {
#pragma unroll
  for (int off = 1; off < 64; off <<= 1) {
    float y = __shfl_up(x, off);
    if (lane >= off) x *= y;
  }
  return x;
}

__global__ __launch_bounds__(256) void nerf_zero(float* acc) {
  if (threadIdx.x < 16) acc[threadIdx.x] = 0.f;
}

__global__ __launch_bounds__(256) void nerf_main(
    const float* __restrict__ density,
    const float* __restrict__ semantic,
    const float* __restrict__ rays,
    const float* __restrict__ bda,
    float* __restrict__ acc_g,
    int nrays) {
  __shared__ float s_t[CHUNKS * 64];   // t values (pad beyond 416 harmless)
  __shared__ float s_dist[RPB][S_TOT];
  __shared__ unsigned long long s_keep[RPB][CHUNKS];
  __shared__ float s_acc[8];           // block-level loss accumulators

  const int lane = threadIdx.x & 63;
  const int wv = threadIdx.x >> 6;
  const int ray = blockIdx.x * RPB + wv;

  // ---- constants matching the reference's numpy derivations ----
  const double BG = (double)(1.0f / 39.0f);          // BG_LEN (f32-rounded)
  const float BGf = (float)BG;
  const float DTH = (float)((2.0 + 2.0 * BG) / 200.0 * 0.5 * 0.95);
  const float xminf = (float)(-1.0 - BG);
  const float xmaxf = (float)(1.0 + BG);
  const float zf = 6.4f / 80.0f;                     // _Z
  const float sxy = 199.0f / (xmaxf - xminf);
  const float szc = 15.0f / (zf + zf);
  const float ACTS = -13.815509557964274f;           // log(1/(1-1e-6)-1)

  if (threadIdx.x < 8) s_acc[threadIdx.x] = 0.f;

  // ---- t table (shared by all rays; computed once per block) ----
  for (int i = threadIdx.x; i < CHUNKS * 64; i += 256) {
    double td;
    if (i < N_IN) {
      td = (2.0 * i + 1.0) / 390.0;
    } else {
      int j = i - N_IN;
      const double stp = (1.0 / 64.0 - 1.0) / 26.0;
      double l0 = 1.0 + j * stp;
      double l1 = (j + 1 >= 26) ? (1.0 / 64.0) : (1.0 + (j + 1) * stp);
      td = 1.0 / l0 + 1.0 / l1;  // (2/l0 + 2/l1)/2
    }
    s_t[i] = (float)td;
  }
  __syncthreads();

  bool doit = false;
  float rox = 0, roy = 0, roz = 0, rdx = 0, rdy = 0, rdz = 0;
  float b00 = 0, b01 = 0, b02 = 0, b10 = 0, b11 = 0, b12 = 0, b20 = 0, b21 = 0, b22 = 0;
  int ysem = 0;
  if (ray < nrays) {
    const float* rp = rays + (size_t)ray * 10;
    float dep = rp[2];
    doit = (dep > 0.f) && (dep <= 52.f);
    ysem = (int)rp[3];
    ysem = ysem < 0 ? 0 : (ysem > NC - 1 ? NC - 1 : ysem);
    const float czc = (-1.0f + 5.4f) * 0.5f;  // scene center z (f32 path)
    rox = rp[4] / 39.0f;
    roy = rp[5] / 39.0f;
    roz = (rp[6] - czc) / 39.0f;
    float d0 = rp[7], d1 = rp[8], d2 = rp[9];
    float rn = sqrtf(d0 * d0 + d1 * d1 + d2 * d2);
    rdx = d0 / rn; rdy = d1 / rn; rdz = d2 / rn;
    b00 = bda[0]; b01 = bda[1]; b02 = bda[2];
    b10 = bda[3]; b11 = bda[4]; b12 = bda[5];
    b20 = bda[6]; b21 = bda[7]; b22 = bda[8];
  }

  // pts at sample s (after squash + bda); inner flag uses pre-squash norm
  auto compute_pt = [&](int s, float& tx, float& ty, float& tz, float& tt,
                        bool& inner) {
    tt = s_t[s];
    float qx = rox + rdx * tt;
    float qy = roy + rdy * tt;
    float qz = roz + rdz * tt;
    float nr = sqrtf(qx * qx + qy * qy + qz * qz);
    inner = (nr <= 1.0f) && (s < S_TOT);
    if (nr > 1.0f) {
      float sc = (1.0f + BGf - BGf / nr) / nr;
      qx *= sc; qy *= sc; qz *= sc;
    }
    tx = b00 * qx + b01 * qy + b02 * qz;
    ty = b10 * qx + b11 * qy + b12 * qz;
    tz = b20 * qx + b21 * qy + b22 * qz;
  };

  // ---- phase A/B: pts, inner ballot, consecutive distances -> LDS ----
  if (doit) {
    for (int c = 0; c < CHUNKS; c++) {
      int s = c * 64 + lane;
      float tx, ty, tz, tt; bool inner;
      compute_pt(s, tx, ty, tz, tt, inner);
      unsigned long long bal = __ballot(inner);
      if (lane == 0) s_keep[wv][c] = bal;  // stash inner mask for the scan
      float nx = __shfl(tx, lane + 1);
      float ny = __shfl(ty, lane + 1);
      float nz = __shfl(tz, lane + 1);
      if (c < CHUNKS - 1) {
        // first sample of next chunk, computed uniformly by all lanes
        float hx, hy, hz, ht; bool hi;
        compute_pt((c + 1) * 64, hx, hy, hz, ht, hi);
        if (lane == 63) { nx = hx; ny = hy; nz = hz; }
      }
      if (s < S_TOT - 1) {
        float ex = nx - tx, ey = ny - ty, ez = nz - tz;
        s_dist[wv][s] = sqrtf(ex * ex + ey * ey + ez * ez);
      }
    }
  }
  __syncthreads();

  // ---- phase C: sequential resetting distance scan (lane 0) -> keep mask ----
  if (doit && lane == 0) {
    float cum = 0.f;
    for (int c = 0; c < CHUNKS; c++) {
      unsigned long long k = s_keep[wv][c];  // inner mask
      int b0 = (c == 0) ? 1 : 0;
      for (int b = b0; b < 64; b++) {
        int s = c * 64 + b;
        if (s >= S_TOT) break;
        cum += s_dist[wv][s - 1];
        if (cum > DTH) { cum = 0.f; k |= (1ull << b); }
      }
      s_keep[wv][c] = k;
    }
  }
  __syncthreads();

  // ---- phase D/E/F: density->alpha, scans, semantic accumulation ----
  float out_sem[NC];
  if (doit) {
#pragma unroll
    for (int j = 0; j < NC; j++) out_sem[j] = 0.f;
    float carry = 1.f, carryW = 0.f, carryWM = 0.f;
    float sum_bi = 0.f, sum_w2 = 0.f, pkcf = 0.f;

    for (int c = 0; c < CHUNKS; c++) {
      int s = c * 64 + lane;
      float tx, ty, tz, tt; bool inner;
      compute_pt(s, tx, ty, tz, tt, inner);
      float m_ = 1.0f - 1.0f / (1.0f + tt);
      bool keep = (s_keep[wv][c] >> lane) & 1ull;

      int ix = 0, iy = 0, iz = 0;
      float fx = 0.f, fy = 0.f, fz = 0.f;
      float a = 0.f;
      if (keep) {
        float gx = (tx - xminf) * sxy;
        float gy = (ty - xminf) * sxy;
        float gz = (tz + zf) * szc;
        float hx = floorf(gx), hy = floorf(gy), hz = floorf(gz);
        ix = (int)hx; iy = (int)hy; iz = (int)hz;
        fx = gx - hx; fy = gy - hy; fz = gz - hz;
        float wx0 = 1.f - fx, wy0 = 1.f - fy, wz0 = 1.f - fz;
        bool vx0 = (unsigned)ix < (unsigned)DXX, vx1 = (unsigned)(ix + 1) < (unsigned)DXX;
        bool vy0 = (unsigned)iy < (unsigned)DYY, vy1 = (unsigned)(iy + 1) < (unsigned)DYY;
        bool vz0 = (unsigned)iz < (unsigned)DZZ, vz1 = (unsigned)(iz + 1) < (unsigned)DZZ;
        float dens = 0.f;
        if (vx0 && vy0 && vz0) dens += wx0 * wy0 * wz0 * density[((size_t)ix * DYY + iy) * DZZ + iz];
        if (vx0 && vy0 && vz1) dens += wx0 * wy0 * fz  * density[((size_t)ix * DYY + iy) * DZZ + iz + 1];
        if (vx0 && vy1 && vz0) dens += wx0 * fy  * wz0 * density[((size_t)ix * DYY + (iy + 1)) * DZZ + iz];
        if (vx0 && vy1 && vz1) dens += wx0 * fy  * fz  * density[((size_t)ix * DYY + (iy + 1)) * DZZ + iz + 1];
        if (vx1 && vy0 && vz0) dens += fx  * wy0 * wz0 * density[((size_t)(ix + 1) * DYY + iy) * DZZ + iz];
        if (vx1 && vy0 && vz1) dens += fx  * wy0 * fz  * density[((size_t)(ix + 1) * DYY + iy) * DZZ + iz + 1];
        if (vx1 && vy1 && vz0) dens += fx  * fy  * wz0 * density[((size_t)(ix + 1) * DYY + (iy + 1)) * DZZ + iz];
        if (vx1 && vy1 && vz1) dens += fx  * fy  * fz  * density[((size_t)(ix + 1) * DYY + (iy + 1)) * DZZ + iz + 1];
        float u = expf(dens + ACTS);
        a = -expm1f(-0.5f * log1pf(u));   // 1-(1+u)^-0.5, no cancellation
        if (!(a > 1e-7f)) a = 0.f;
      }

      // transmittance cumprod (chunked scan + carry)
      float om = 1.f - a;
      float ip = iscan_mul(om, lane);
      float ex = __shfl_up(ip, 1); if (lane == 0) ex = 1.f;
      float wgt = a * carry * ex;
      carry *= __shfl(ip, 63);
      float w = (wgt > 1e-7f) ? wgt : 0.f;
      if (w > 0.f) pkcf += 1.f;

      // distortion-loss cumsums (exclusive)
      float wm = w * m_;
      float isw = iscan_add(w, lane);
      float iswm = iscan_add(wm, lane);
      float exw = __shfl_up(isw, 1);  if (lane == 0) exw = 0.f;
      float exwm = __shfl_up(iswm, 1); if (lane == 0) exwm = 0.f;
      sum_bi += 2.f * w * (m_ * (carryW + exw) - (carryWM + exwm));
      sum_w2 += w * w;
      carryW += __shfl(isw, 63);
      carryWM += __shfl(iswm, 63);

      // semantic trilinear, only where weight survives.
      // 17 contiguous floats per corner -> 4x unaligned float4 + 1 scalar
      // (same bytes/order as the scalar version; ~3x fewer VMEM requests).
      if (w > 0.f) {
        float wx0 = 1.f - fx, wy0 = 1.f - fy, wz0 = 1.f - fz;
        bool vx0 = (unsigned)ix < (unsigned)DXX, vx1 = (unsigned)(ix + 1) < (unsigned)DXX;
        bool vy0 = (unsigned)iy < (unsigned)DYY, vy1 = (unsigned)(iy + 1) < (unsigned)DYY;
        bool vz0 = (unsigned)iz < (unsigned)DZZ, vz1 = (unsigned)(iz + 1) < (unsigned)DZZ;
#define SEM_CORNER(V, WX, WY, WZ, XI, YI, ZI)                                      \
        if (V) {                                                                    \
          float wc = w * (WX) * (WY) * (WZ);                                        \
          const float* sp = semantic + (((size_t)(XI) * DYY + (YI)) * DZZ + (ZI)) * NC; \
          const v4u* sp4 = (const v4u*)sp;                                          \
          v4u q0 = sp4[0], q1 = sp4[1], q2 = sp4[2], q3 = sp4[3];                   \
          float qs = sp[16];                                                        \
          out_sem[0]  += wc * q0[0];  out_sem[1]  += wc * q0[1];                    \
          out_sem[2]  += wc * q0[2];  out_sem[3]  += wc * q0[3];                    \
          out_sem[4]  += wc * q1[0];  out_sem[5]  += wc * q1[1];                    \
          out_sem[6]  += wc * q1[2];  out_sem[7]  += wc * q1[3];                    \
          out_sem[8]  += wc * q2[0];  out_sem[9]  += wc * q2[1];                    \
          out_sem[10] += wc * q2[2];  out_sem[11] += wc * q2[3];                    \
          out_sem[12] += wc * q3[0];  out_sem[13] += wc * q3[1];                    \
          out_sem[14] += wc * q3[2];  out_sem[15] += wc * q3[3];                    \
          out_sem[16] += wc * qs;                                                   \
        }
        SEM_CORNER(vx0 && vy0 && vz0, wx0, wy0, wz0, ix, iy, iz)
        SEM_CORNER(vx0 && vy0 && vz1, wx0, wy0, fz,  ix, iy, iz + 1)
        SEM_CORNER(vx0 && vy1 && vz0, wx0, fy,  wz0, ix, iy + 1, iz)
        SEM_CORNER(vx0 && vy1 && vz1, wx0, fy,  fz,  ix, iy + 1, iz + 1)
        SEM_CORNER(vx1 && vy0 && vz0, fx,  wy0, wz0, ix + 1, iy, iz)
        SEM_CORNER(vx1 && vy0 && vz1, fx,  wy0, fz,  ix + 1, iy, iz + 1)
        SEM_CORNER(vx1 && vy1 && vz0, fx,  fy,  wz0, ix + 1, iy + 1, iz)
        SEM_CORNER(vx1 && vy1 && vz1, fx,  fy,  fz,  ix + 1, iy + 1, iz + 1)
#undef SEM_CORNER
      }
    }

    // ---- phase G: wave reductions + per-ray epilogue -> block LDS acc ----
    float r0 = sum_bi, r1 = sum_w2, r2 = pkcf;
#pragma unroll
    for (int off = 32; off >= 1; off >>= 1) {
      r0 += __shfl_xor(r0, off);
      r1 += __shfl_xor(r1, off);
      r2 += __shfl_xor(r2, off);
#pragma unroll
      for (int j = 0; j < NC; j++) out_sem[j] += __shfl_xor(out_sem[j], off);
    }
    if (lane == 0) {
      float M = out_sem[0];
#pragma unroll
      for (int j = 1; j < NC; j++) M = fmaxf(M, out_sem[j]);
      float se = 0.f;
#pragma unroll
      for (int j = 0; j < NC; j++) se += expf(out_sem[j] - M);
      float lse = M + logf(se);
      float sy = 0.f;
#pragma unroll
      for (int j = 0; j < NC; j++) if (j == ysem) sy = out_sem[j];
      float nll = lse - sy;
      float cw = (float)(1.0 / log(c_freq[ysem] + 0.001));
      float p = fminf(fmaxf(carry, 1e-6f), 1.0f - 1e-6f);
      float ent = -(p * logf(p) + (1.f - p) * logf(1.f - p));
      atomicAdd(&s_acc[0], cw * nll);
      atomicAdd(&s_acc[1], cw);
      atomicAdd(&s_acc[2], ent);
      atomicAdd(&s_acc[3], 1.f);
      atomicAdd(&s_acc[4], r0);
      atomicAdd(&s_acc[5], r1);
      atomicAdd(&s_acc[6], r2);
    }
  }

  // block-level pre-reduction -> one set of global atomics per block
  __syncthreads();
  if (threadIdx.x == 0 && s_acc[3] > 0.f) {
#pragma unroll
    for (int i = 0; i < 7; i++) atomicAdd(&acc_g[i], s_acc[i]);
  }
}

__global__ __launch_bounds__(64) void nerf_fin(const float* __restrict__ acc,
                                               float* __restrict__ out) {
  if (threadIdx.x == 0) {
    float ls = acc[0] / fmaxf(acc[1], 1e-12f);
    float nv = fmaxf(acc[3], 1.f);
    float le = acc[2] / nv;
    float nmax = fmaxf(acc[6], 1.f);
    float ld = (acc[4] + (1.f / 3.f) * (1.f / nmax) * acc[5]) / nv;
    out[0] = 1.0f * ls;    // W_SEM
    out[1] = 0.01f * le;   // W_ENT
    out[2] = 0.01f * ld;   // W_DIST
  }
}

extern "C" void kernel_launch(void* const* d_in, const int* in_sizes, int n_in,
                              void* d_out, int out_size, void* d_ws, size_t ws_size,
                              hipStream_t stream) {
  const float* density = (const float*)d_in[0];
  const float* semantic = (const float*)d_in[1];
  const float* rays = (const float*)d_in[2];
  const float* bda = (const float*)d_in[3];
  float* out = (float*)d_out;
  float* acc = (float*)d_ws;
  int nrays = in_sizes[2] / 10;
  nerf_zero<<<1, 256, 0, stream>>>(acc);
  int nb = (nrays + RPB - 1) / RPB;
  nerf_main<<<nb, 64 * RPB, 0, stream>>>(density, semantic, rays, bda, acc, nrays);
  nerf_fin<<<1, 64, 0, stream>>>(acc, out);
}